// Round 5
// baseline (421.309 us; speedup 1.0000x reference)
//
#include <hip/hip_runtime.h>
#include <hip/hip_bf16.h>

typedef unsigned short u16;
typedef __bf16 bf16x8 __attribute__((ext_vector_type(8)));
typedef u16 u16x8 __attribute__((ext_vector_type(8)));
typedef float f32x4 __attribute__((ext_vector_type(4)));

__device__ __forceinline__ float bf2f(u16 u) {
    return __uint_as_float(((unsigned)u) << 16);
}
__device__ __forceinline__ u16 f2bf(float f) {
    unsigned u = __float_as_uint(f);
    unsigned r = (u + 0x7fffu + ((u >> 16) & 1u)) >> 16;
    return (u16)r;
}

// async global->LDS, 16B per lane. dst is wave-uniform base; HW adds lane*16.
__device__ __forceinline__ void gl_lds16(const u16* g, u16* l) {
    __builtin_amdgcn_global_load_lds(
        (const __attribute__((address_space(1))) void*)g,
        (__attribute__((address_space(3))) void*)l, 16, 0, 0);
}

// ---------------- fp32 -> bf16 bulk convert (8 elems/thread) ----------------
__global__ __launch_bounds__(256) void f32_to_bf16(const float* __restrict__ in,
                                                   u16* __restrict__ out, int n) {
    int i = (blockIdx.x * 256 + threadIdx.x) * 8;
    if (i + 8 > n) return;
    float4 a = *(const float4*)&in[i];
    float4 b = *(const float4*)&in[i + 4];
    u16x8 o;
    o[0] = f2bf(a.x); o[1] = f2bf(a.y); o[2] = f2bf(a.z); o[3] = f2bf(a.w);
    o[4] = f2bf(b.x); o[5] = f2bf(b.y); o[6] = f2bf(b.z); o[7] = f2bf(b.w);
    *(u16x8*)&out[i] = o;
}

// ---------------- transpose+convert: W fp32 [K][N] -> WT bf16 [N][K] ----------------
__global__ __launch_bounds__(256) void transpose_f32_bf16(const float* __restrict__ W,
                                                          u16* __restrict__ WT,
                                                          int K, int N) {
    __shared__ float tile[64][65];
    const int nt = N >> 6;
    const int k0 = (blockIdx.x / nt) << 6;
    const int n0 = (blockIdx.x % nt) << 6;
    for (int i = threadIdx.x; i < 4096; i += 256) {
        int r = i >> 6, c = i & 63;
        tile[r][c] = W[(size_t)(k0 + r) * N + n0 + c];
    }
    __syncthreads();
    for (int i = threadIdx.x; i < 4096; i += 256) {
        int r = i >> 6, c = i & 63;
        WT[(size_t)(n0 + r) * K + k0 + c] = f2bf(tile[c][r]);
    }
}

// ---------------- MFMA GEMM: C[M][N] = rowmap(A)[M][K] @ Bt[N][K]^T (+bias) ----------
// m97 structure: 128x128 tile, BK=64, global_load_lds width 16, linear LDS.
// T1: bijective XCD-chunked block swizzle (nwg % 8 == 0 for all our grids).
// MODE 0: row r -> r (clamp). MODE 1: r -> (r/256)*257+(r%256)+1 (exact).
// MODE 2: r -> r*257 (clamp). OUTF: store float (+bias), else bf16.
template <int MODE, int OUTF>
__global__ __launch_bounds__(256) void gemm_k(const u16* __restrict__ A,
                                              const u16* __restrict__ Bt,
                                              void* __restrict__ Cv,
                                              const float* __restrict__ bias,
                                              int M, int N, int K) {
    __shared__ u16 As[128][64];
    __shared__ u16 Bs[128][64];
    const int t = threadIdx.x;
    // XCD swizzle: orig block b runs on XCD b%8; give each XCD a contiguous
    // chunk of logical tile space so same-M-panel tiles share one L2.
    const int nwg = gridDim.x * gridDim.y;
    int bid = blockIdx.y * gridDim.x + blockIdx.x;
    if ((nwg & 7) == 0) bid = (bid & 7) * (nwg >> 3) + (bid >> 3);
    const int bn0 = (bid % gridDim.x) * 128;
    const int bm0 = (bid / gridDim.x) * 128;
    const int wave = t >> 6, lane = t & 63;
    const int wm = (wave >> 1) * 64, wn = (wave & 1) * 64;
    const int lr = lane & 15, lh = lane >> 4;

    // staging geometry: issue i covers rows i*32 + wave*8 + (lane>>3), col (lane&7)*8
    const int srow = wave * 8 + (lane >> 3);
    const int scol = (lane & 7) * 8;

    f32x4 acc[4][4] = {};

    for (int kt = 0; kt < K; kt += 64) {
        __syncthreads();
#pragma unroll
        for (int i = 0; i < 4; i++) {
            int row = i * 32 + srow;
            int r = bm0 + row;
            long g;
            if (MODE == 0)      g = (r < M) ? (long)r : 0l;
            else if (MODE == 1) g = (long)(r >> 8) * 257 + (r & 255) + 1;
            else                g = (r < M) ? (long)r * 257 : 0l;
            gl_lds16(&A[g * K + kt + scol], &As[0][0] + i * 2048 + wave * 512);
            long nr = bn0 + row;
            gl_lds16(&Bt[nr * K + kt + scol], &Bs[0][0] + i * 2048 + wave * 512);
        }
        __syncthreads();
#pragma unroll
        for (int kk = 0; kk < 2; kk++) {
            bf16x8 af[4], bfr[4];
#pragma unroll
            for (int mi = 0; mi < 4; mi++)
                af[mi] = *(const bf16x8*)&As[wm + mi * 16 + lr][kk * 32 + lh * 8];
#pragma unroll
            for (int ni = 0; ni < 4; ni++)
                bfr[ni] = *(const bf16x8*)&Bs[wn + ni * 16 + lr][kk * 32 + lh * 8];
#pragma unroll
            for (int mi = 0; mi < 4; mi++)
#pragma unroll
                for (int ni = 0; ni < 4; ni++)
                    acc[mi][ni] = __builtin_amdgcn_mfma_f32_16x16x32_bf16(
                        af[mi], bfr[ni], acc[mi][ni], 0, 0, 0);
        }
    }

#pragma unroll
    for (int mi = 0; mi < 4; mi++) {
#pragma unroll
        for (int ni = 0; ni < 4; ni++) {
#pragma unroll
            for (int r2 = 0; r2 < 4; r2++) {
                int m = bm0 + wm + mi * 16 + lh * 4 + r2;
                if (m < M) {
                    int nc = bn0 + wn + ni * 16 + lr;
                    float v = acc[mi][ni][r2];
                    if (OUTF) {
                        ((float*)Cv)[(size_t)m * N + nc] = v + bias[nc];
                    } else {
                        ((u16*)Cv)[(size_t)m * N + nc] = f2bf(v);
                    }
                }
            }
        }
    }
}

// ---------------- attention av: qa(5x64) @ kv(1280x64)^T -> softmax -> @ vv ----------
// one block per (bi,hd), bi in [0,32); 1024 threads = 16 waves for TLP.
__global__ __launch_bounds__(1024) void attn_av(const u16* __restrict__ vqkv,
                                                const u16* __restrict__ aqkv,
                                                u16* __restrict__ cat) {
    __shared__ float qa[5][64];
    __shared__ float p[5][1280];
    __shared__ float pbuf[16][5][64];
    const int bi = blockIdx.x >> 3, hd = blockIdx.x & 7;
    const int t = threadIdx.x;
    if (t < 320) {
        int tt = t >> 6, d = t & 63;
        qa[tt][d] = bf2f(aqkv[(size_t)(bi * 5 + tt) * 1536 + hd * 64 + d]);
    }
    __syncthreads();
    // phase 1: scores (1280 keys over 1024 threads)
    for (int s = t; s < 1280; s += 1024) {
        int j = s / 5, t5 = s - j * 5;
        const u16* row = &vqkv[(size_t)((bi * 5 + t5) * 256 + j) * 1536 + 512 + hd * 64];
        float a0 = 0, a1 = 0, a2 = 0, a3 = 0, a4 = 0;
#pragma unroll
        for (int d = 0; d < 64; d += 8) {
            u16x8 v8 = *(const u16x8*)&row[d];
#pragma unroll
            for (int jj = 0; jj < 8; jj++) {
                float f = bf2f(v8[jj]);
                a0 += f * qa[0][d + jj];
                a1 += f * qa[1][d + jj];
                a2 += f * qa[2][d + jj];
                a3 += f * qa[3][d + jj];
                a4 += f * qa[4][d + jj];
            }
        }
        p[0][s] = a0 * 0.125f; p[1][s] = a1 * 0.125f; p[2][s] = a2 * 0.125f;
        p[3][s] = a3 * 0.125f; p[4][s] = a4 * 0.125f;
    }
    __syncthreads();
    const int wave = t >> 6, lane = t & 63;
    // phase 2: softmax, waves 0..4 handle rows 0..4
    if (wave < 5) {
        float mx = -3.4e38f;
        for (int s = lane; s < 1280; s += 64) mx = fmaxf(mx, p[wave][s]);
#pragma unroll
        for (int off = 32; off > 0; off >>= 1) mx = fmaxf(mx, __shfl_xor(mx, off));
        float sum = 0.f;
        for (int s = lane; s < 1280; s += 64) {
            float e = __expf(p[wave][s] - mx);
            p[wave][s] = e;
            sum += e;
        }
#pragma unroll
        for (int off = 32; off > 0; off >>= 1) sum += __shfl_xor(sum, off);
        float inv = 1.f / sum;
        for (int s = lane; s < 1280; s += 64) p[wave][s] *= inv;
    }
    __syncthreads();
    // phase 3: wave w owns s in [w*80, (w+1)*80); lane = d; 5 accs in registers.
    {
        float a0 = 0, a1 = 0, a2 = 0, a3 = 0, a4 = 0;
        const int s0 = wave * 80;
        for (int s = s0; s < s0 + 80; s++) {
            int j = s / 5, t5 = s - j * 5;
            float v = bf2f(vqkv[(size_t)((bi * 5 + t5) * 256 + j) * 1536 + 1024 + hd * 64 + lane]);
            a0 += p[0][s] * v;
            a1 += p[1][s] * v;
            a2 += p[2][s] * v;
            a3 += p[3][s] * v;
            a4 += p[4][s] * v;
        }
        pbuf[wave][0][lane] = a0;
        pbuf[wave][1][lane] = a1;
        pbuf[wave][2][lane] = a2;
        pbuf[wave][3][lane] = a3;
        pbuf[wave][4][lane] = a4;
    }
    __syncthreads();
    if (t < 320) {
        int t5 = t >> 6, d = t & 63;
        float s = 0.f;
#pragma unroll
        for (int w = 0; w < 16; w++) s += pbuf[w][t5][d];
        cat[(size_t)((bi * 5 + t5) * 257) * 512 + hd * 64 + d] = f2bf(s);
    }
}

// ---------------- attention va: thread-per-query, no cross-lane ops -----------------
// grid 1280 = 5 chunks x (32 bi x 8 hd); each thread owns one query s = chunk*256 + tid
__global__ __launch_bounds__(256) void attn_va(const u16* __restrict__ vqkv,
                                               const u16* __restrict__ aqkv,
                                               const float* __restrict__ mask,
                                               u16* __restrict__ cat) {
    __shared__ float ka[5][64], vaS[5][64];
    const int blk = blockIdx.x;
    const int chunk = blk % 5;
    const int bh = blk / 5;                 // 0..255
    const int bi = bh >> 3, hd = bh & 7;    // bi in [0,32)
    const int t = threadIdx.x;
    for (int i = t; i < 320; i += 256) {
        int tt = i >> 6, d = i & 63;
        ka[tt][d]  = bf2f(aqkv[(size_t)(bi * 5 + tt) * 1536 + 512 + hd * 64 + d]);
        vaS[tt][d] = bf2f(aqkv[(size_t)(bi * 5 + tt) * 1536 + 1024 + hd * 64 + d]);
    }
    __syncthreads();
    const int s = chunk * 256 + t;          // 0..1279
    const int j = s / 5, t5 = s - j * 5;
    const int row = (bi * 5 + t5) * 256 + j;
    const u16* qrow = &vqkv[(size_t)row * 1536 + hd * 64];
    float r0 = 0, r1 = 0, r2 = 0, r3 = 0, r4 = 0;
#pragma unroll
    for (int d = 0; d < 64; d += 8) {
        u16x8 q8 = *(const u16x8*)&qrow[d];
#pragma unroll
        for (int jj = 0; jj < 8; jj++) {
            float f = bf2f(q8[jj]);
            r0 += f * ka[0][d + jj];
            r1 += f * ka[1][d + jj];
            r2 += f * ka[2][d + jj];
            r3 += f * ka[3][d + jj];
            r4 += f * ka[4][d + jj];
        }
    }
    const float mval = mask[row] * 0.125f;
    r0 *= mval; r1 *= mval; r2 *= mval; r3 *= mval; r4 *= mval;
    float mx = fmaxf(fmaxf(fmaxf(r0, r1), fmaxf(r2, r3)), r4);
    float e0 = __expf(r0 - mx), e1 = __expf(r1 - mx), e2 = __expf(r2 - mx);
    float e3 = __expf(r3 - mx), e4 = __expf(r4 - mx);
    const float inv = 1.f / (e0 + e1 + e2 + e3 + e4);
    e0 *= inv; e1 *= inv; e2 *= inv; e3 *= inv; e4 *= inv;
    const size_t orow = ((size_t)((bi * 5 + t5) * 257) + 1 + j) * 512 + hd * 64;
#pragma unroll
    for (int d = 0; d < 64; d += 8) {
        u16x8 o8;
#pragma unroll
        for (int jj = 0; jj < 8; jj++) {
            float o = e0 * vaS[0][d + jj] + e1 * vaS[1][d + jj] + e2 * vaS[2][d + jj] +
                      e3 * vaS[3][d + jj] + e4 * vaS[4][d + jj];
            o8[jj] = f2bf(o);
        }
        *(u16x8*)&cat[orow + d] = o8;
    }
}

extern "C" void kernel_launch(void* const* d_in, const int* in_sizes, int n_in,
                              void* d_out, int out_size, void* d_ws, size_t ws_size,
                              hipStream_t stream) {
    const float* x    = (const float*)d_in[0];  // (160,257,512) f32
    const float* mask = (const float*)d_in[1];  // (160,256) f32
    const float* Wv   = (const float*)d_in[2];  // (512,1536) f32
    const float* Wa   = (const float*)d_in[3];  // (512,1536) f32
    const float* Wo   = (const float*)d_in[4];  // (512,512) f32
    const float* bo   = (const float*)d_in[5];  // (512,) f32
    float* out = (float*)d_out;

    char* ws = (char*)d_ws;
    u16* xb   = (u16*)(ws);                   // 41120*512*2 = 42,106,880 B
    u16* WvT  = (u16*)(ws + 42106880);        // 1,572,864 B
    u16* WaT  = (u16*)(ws + 43679744);        // 1,572,864 B
    u16* WoT  = (u16*)(ws + 45252608);        //   524,288 B
    u16* aqkv = (u16*)(ws + 45776896);        //   491,520 B
    u16* vqkv = (u16*)(ws + 46268416);        // 40960*1536*2 = 125,829,120 B
    u16* cat  = (u16*)(ws + 172097536);       // 42,106,880 B  -> total ~214.2 MB

    f32_to_bf16<<<dim3(10280), 256, 0, stream>>>(x, xb, 41120 * 512);
    transpose_f32_bf16<<<dim3(192), 256, 0, stream>>>(Wv, WvT, 512, 1536);
    transpose_f32_bf16<<<dim3(192), 256, 0, stream>>>(Wa, WaT, 512, 1536);
    transpose_f32_bf16<<<dim3(64),  256, 0, stream>>>(Wo, WoT, 512, 512);

    // v_qkv = V @ Wv_qkv   (V rows = xb[i*257 + 1 + j])
    gemm_k<1, 0><<<dim3(12, 320), 256, 0, stream>>>(xb, WvT, vqkv, nullptr, 40960, 1536, 512);
    // a_qkv = A @ Wa_qkv   (A rows = xb[i*257])
    gemm_k<2, 0><<<dim3(12, 2), 256, 0, stream>>>(xb, WaT, aqkv, nullptr, 160, 1536, 512);

    attn_av<<<dim3(256), 1024, 0, stream>>>(vqkv, aqkv, cat);
    attn_va<<<dim3(1280), 256, 0, stream>>>(vqkv, aqkv, mask, cat);

    // out = cat @ Wo + bo   (float out)
    gemm_k<0, 1><<<dim3(4, 322), 256, 0, stream>>>(cat, WoT, out, bo, 41120, 512, 512);
}

// Round 6
// 310.415 us; speedup vs baseline: 1.3572x; 1.3572x over previous
//
#include <hip/hip_runtime.h>
#include <hip/hip_bf16.h>

typedef unsigned short u16;
typedef __bf16 bf16x8 __attribute__((ext_vector_type(8)));
typedef u16 u16x8 __attribute__((ext_vector_type(8)));
typedef float f32x4 __attribute__((ext_vector_type(4)));

__device__ __forceinline__ float bf2f(u16 u) {
    return __uint_as_float(((unsigned)u) << 16);
}
__device__ __forceinline__ u16 f2bf(float f) {
    unsigned u = __float_as_uint(f);
    unsigned r = (u + 0x7fffu + ((u >> 16) & 1u)) >> 16;
    return (u16)r;
}

// async global->LDS, 16B per lane. dst is wave-uniform base; HW adds lane*16.
__device__ __forceinline__ void gl_lds16(const u16* g, u16* l) {
    __builtin_amdgcn_global_load_lds(
        (const __attribute__((address_space(1))) void*)g,
        (__attribute__((address_space(3))) void*)l, 16, 0, 0);
}

// ---------------- fp32 -> bf16 bulk convert (8 elems/thread) ----------------
__global__ __launch_bounds__(256) void f32_to_bf16(const float* __restrict__ in,
                                                   u16* __restrict__ out, int n) {
    int i = (blockIdx.x * 256 + threadIdx.x) * 8;
    if (i + 8 > n) return;
    float4 a = *(const float4*)&in[i];
    float4 b = *(const float4*)&in[i + 4];
    u16x8 o;
    o[0] = f2bf(a.x); o[1] = f2bf(a.y); o[2] = f2bf(a.z); o[3] = f2bf(a.w);
    o[4] = f2bf(b.x); o[5] = f2bf(b.y); o[6] = f2bf(b.z); o[7] = f2bf(b.w);
    *(u16x8*)&out[i] = o;
}

// ---------------- transpose+convert: W fp32 [K][N] -> WT bf16 [N][K] ----------------
__global__ __launch_bounds__(256) void transpose_f32_bf16(const float* __restrict__ W,
                                                          u16* __restrict__ WT,
                                                          int K, int N) {
    __shared__ float tile[64][65];
    const int nt = N >> 6;
    const int k0 = (blockIdx.x / nt) << 6;
    const int n0 = (blockIdx.x % nt) << 6;
    for (int i = threadIdx.x; i < 4096; i += 256) {
        int r = i >> 6, c = i & 63;
        tile[r][c] = W[(size_t)(k0 + r) * N + n0 + c];
    }
    __syncthreads();
    for (int i = threadIdx.x; i < 4096; i += 256) {
        int r = i >> 6, c = i & 63;
        WT[(size_t)(n0 + r) * K + k0 + c] = f2bf(tile[c][r]);
    }
}

// ---------------- MFMA GEMM: C[M][N] = rowmap(A)[M][K] @ Bt[N][K]^T (+bias) ----------
// m97 structure: 128x128 tile, BK=64, global_load_lds width 16, linear LDS.
// MODE 0: row r -> r (clamp). MODE 1: r -> (r/256)*257+(r%256)+1 (exact).
// MODE 2: r -> r*257 (clamp). OUTF: store float (+bias), else bf16.
template <int MODE, int OUTF>
__global__ __launch_bounds__(256) void gemm_k(const u16* __restrict__ A,
                                              const u16* __restrict__ Bt,
                                              void* __restrict__ Cv,
                                              const float* __restrict__ bias,
                                              int M, int N, int K) {
    __shared__ u16 As[128][64];
    __shared__ u16 Bs[128][64];
    const int t = threadIdx.x;
    const int bn0 = blockIdx.x * 128;
    const int bm0 = blockIdx.y * 128;
    const int wave = t >> 6, lane = t & 63;
    const int wm = (wave >> 1) * 64, wn = (wave & 1) * 64;
    const int lr = lane & 15, lh = lane >> 4;

    // staging geometry: issue i covers rows i*32 + wave*8 + (lane>>3), col (lane&7)*8
    const int srow = wave * 8 + (lane >> 3);
    const int scol = (lane & 7) * 8;

    f32x4 acc[4][4] = {};

    for (int kt = 0; kt < K; kt += 64) {
        __syncthreads();
#pragma unroll
        for (int i = 0; i < 4; i++) {
            int row = i * 32 + srow;
            int r = bm0 + row;
            long g;
            if (MODE == 0)      g = (r < M) ? (long)r : 0l;
            else if (MODE == 1) g = (long)(r >> 8) * 257 + (r & 255) + 1;
            else                g = (r < M) ? (long)r * 257 : 0l;
            gl_lds16(&A[g * K + kt + scol], &As[0][0] + i * 2048 + wave * 512);
            long nr = bn0 + row;
            gl_lds16(&Bt[nr * K + kt + scol], &Bs[0][0] + i * 2048 + wave * 512);
        }
        __syncthreads();
#pragma unroll
        for (int kk = 0; kk < 2; kk++) {
            bf16x8 af[4], bfr[4];
#pragma unroll
            for (int mi = 0; mi < 4; mi++)
                af[mi] = *(const bf16x8*)&As[wm + mi * 16 + lr][kk * 32 + lh * 8];
#pragma unroll
            for (int ni = 0; ni < 4; ni++)
                bfr[ni] = *(const bf16x8*)&Bs[wn + ni * 16 + lr][kk * 32 + lh * 8];
#pragma unroll
            for (int mi = 0; mi < 4; mi++)
#pragma unroll
                for (int ni = 0; ni < 4; ni++)
                    acc[mi][ni] = __builtin_amdgcn_mfma_f32_16x16x32_bf16(
                        af[mi], bfr[ni], acc[mi][ni], 0, 0, 0);
        }
    }

#pragma unroll
    for (int mi = 0; mi < 4; mi++) {
#pragma unroll
        for (int ni = 0; ni < 4; ni++) {
#pragma unroll
            for (int r2 = 0; r2 < 4; r2++) {
                int m = bm0 + wm + mi * 16 + lh * 4 + r2;
                if (m < M) {
                    int nc = bn0 + wn + ni * 16 + lr;
                    float v = acc[mi][ni][r2];
                    if (OUTF) {
                        ((float*)Cv)[(size_t)m * N + nc] = v + bias[nc];
                    } else {
                        ((u16*)Cv)[(size_t)m * N + nc] = f2bf(v);
                    }
                }
            }
        }
    }
}

// ============ attention av, 4-kernel decomposition =============================
// rid(bi,hd,q) = ((bi*8+hd)*5+q), rows of pglob[1280][1280] / avout[1280][64]

// --- K1: scores. grid 1280 = chunk(5) x (bi,hd)(256); thread-per-key ---
__global__ __launch_bounds__(256) void av_scores(const u16* __restrict__ vqkv,
                                                 const u16* __restrict__ aqkv,
                                                 float* __restrict__ pglob) {
    __shared__ float qa[5][64];
    const int blk = blockIdx.x;
    const int chunk = blk % 5;
    const int bh = blk / 5;                 // 0..255
    const int bi = bh >> 3, hd = bh & 7;
    const int t = threadIdx.x;
    for (int i = t; i < 320; i += 256) {
        int tt = i >> 6, d = i & 63;
        qa[tt][d] = bf2f(aqkv[(size_t)(bi * 5 + tt) * 1536 + hd * 64 + d]);
    }
    __syncthreads();
    const int s = chunk * 256 + t;          // 0..1279
    const int j = s / 5, t5 = s - j * 5;
    const u16* krow = &vqkv[(size_t)((bi * 5 + t5) * 256 + j) * 1536 + 512 + hd * 64];
    float a0 = 0, a1 = 0, a2 = 0, a3 = 0, a4 = 0;
#pragma unroll
    for (int d = 0; d < 64; d += 8) {
        u16x8 v8 = *(const u16x8*)&krow[d];
#pragma unroll
        for (int jj = 0; jj < 8; jj++) {
            float f = bf2f(v8[jj]);
            a0 += f * qa[0][d + jj];
            a1 += f * qa[1][d + jj];
            a2 += f * qa[2][d + jj];
            a3 += f * qa[3][d + jj];
            a4 += f * qa[4][d + jj];
        }
    }
    const size_t base = (size_t)bh * 5 * 1280 + s;
    pglob[base]          = a0 * 0.125f;
    pglob[base + 1280]   = a1 * 0.125f;
    pglob[base + 2560]   = a2 * 0.125f;
    pglob[base + 3840]   = a3 * 0.125f;
    pglob[base + 5120]   = a4 * 0.125f;
}

// --- K2: softmax in place. wave-per-row; grid 320 x 256 thr (4 waves) ---
__global__ __launch_bounds__(256) void av_softmax(float* __restrict__ pglob) {
    const int wave = threadIdx.x >> 6, lane = threadIdx.x & 63;
    const int rid = blockIdx.x * 4 + wave;  // 0..1279
    float* row = pglob + (size_t)rid * 1280;
    float v[20];
    float mx = -3.4e38f;
#pragma unroll
    for (int i = 0; i < 20; i++) {
        v[i] = row[lane + i * 64];
        mx = fmaxf(mx, v[i]);
    }
#pragma unroll
    for (int off = 32; off > 0; off >>= 1) mx = fmaxf(mx, __shfl_xor(mx, off));
    float sum = 0.f;
#pragma unroll
    for (int i = 0; i < 20; i++) {
        v[i] = __expf(v[i] - mx);
        sum += v[i];
    }
#pragma unroll
    for (int off = 32; off > 0; off >>= 1) sum += __shfl_xor(sum, off);
    const float inv = 1.f / sum;
#pragma unroll
    for (int i = 0; i < 20; i++) row[lane + i * 64] = v[i] * inv;
}

// --- K3: PV partials. grid 2048 = (bi,hd)(256) x jc(8); 320 thr, wave=q, lane=d ---
__global__ __launch_bounds__(320) void av_pv(const u16* __restrict__ vqkv,
                                             const float* __restrict__ pglob,
                                             float* __restrict__ avpart) {
    __shared__ float pl[5][160];
    const int blk = blockIdx.x;
    const int jc = blk & 7;
    const int bh = blk >> 3;                // 0..255
    const int bi = bh >> 3, hd = bh & 7;
    const int t = threadIdx.x;
    // stage p chunk: rows rid(bh,q), cols [jc*160, jc*160+160)
    for (int ii = t; ii < 800; ii += 320) {
        int q = ii / 160, i = ii - q * 160;
        pl[q][i] = pglob[((size_t)bh * 5 + q) * 1280 + jc * 160 + i];
    }
    __syncthreads();
    const int wave = t >> 6, lane = t & 63;   // wave = q
    float acc = 0.f;
    const int j0 = jc * 32;
    for (int jj = 0; jj < 32; jj++) {
        const int j = j0 + jj;
#pragma unroll
        for (int t5 = 0; t5 < 5; t5++) {
            float v = bf2f(vqkv[(size_t)((bi * 5 + t5) * 256 + j) * 1536 + 1024 + hd * 64 + lane]);
            acc += pl[wave][jj * 5 + t5] * v;
        }
    }
    avpart[((size_t)jc * 1280 + (size_t)bh * 5 + wave) * 64 + lane] = acc;
}

// --- K4: reduce partials -> cat A-rows. grid 320 x 256 thr ---
__global__ __launch_bounds__(256) void av_write(const float* __restrict__ avpart,
                                                u16* __restrict__ cat) {
    const int idx = blockIdx.x * 256 + threadIdx.x;   // 0..81919
    const int d = idx & 63;
    const int r = idx >> 6;                           // 0..1279 = bh*5+q
    const int q = r % 5, bh = r / 5;
    const int bi = bh >> 3, hd = bh & 7;
    float s = 0.f;
#pragma unroll
    for (int jc = 0; jc < 8; jc++) s += avpart[((size_t)jc * 1280 + r) * 64 + d];
    cat[(size_t)((bi * 5 + q) * 257) * 512 + hd * 64 + d] = f2bf(s);
}

// ---------------- attention va: thread-per-query, no cross-lane ops -----------------
// grid 1280 = 5 chunks x (32 bi x 8 hd); each thread owns one query s = chunk*256 + tid
__global__ __launch_bounds__(256) void attn_va(const u16* __restrict__ vqkv,
                                               const u16* __restrict__ aqkv,
                                               const float* __restrict__ mask,
                                               u16* __restrict__ cat) {
    __shared__ float ka[5][64], vaS[5][64];
    const int blk = blockIdx.x;
    const int chunk = blk % 5;
    const int bh = blk / 5;                 // 0..255
    const int bi = bh >> 3, hd = bh & 7;    // bi in [0,32)
    const int t = threadIdx.x;
    for (int i = t; i < 320; i += 256) {
        int tt = i >> 6, d = i & 63;
        ka[tt][d]  = bf2f(aqkv[(size_t)(bi * 5 + tt) * 1536 + 512 + hd * 64 + d]);
        vaS[tt][d] = bf2f(aqkv[(size_t)(bi * 5 + tt) * 1536 + 1024 + hd * 64 + d]);
    }
    __syncthreads();
    const int s = chunk * 256 + t;          // 0..1279
    const int j = s / 5, t5 = s - j * 5;
    const int row = (bi * 5 + t5) * 256 + j;
    const u16* qrow = &vqkv[(size_t)row * 1536 + hd * 64];
    float r0 = 0, r1 = 0, r2 = 0, r3 = 0, r4 = 0;
#pragma unroll
    for (int d = 0; d < 64; d += 8) {
        u16x8 q8 = *(const u16x8*)&qrow[d];
#pragma unroll
        for (int jj = 0; jj < 8; jj++) {
            float f = bf2f(q8[jj]);
            r0 += f * ka[0][d + jj];
            r1 += f * ka[1][d + jj];
            r2 += f * ka[2][d + jj];
            r3 += f * ka[3][d + jj];
            r4 += f * ka[4][d + jj];
        }
    }
    const float mval = mask[row] * 0.125f;
    r0 *= mval; r1 *= mval; r2 *= mval; r3 *= mval; r4 *= mval;
    float mx = fmaxf(fmaxf(fmaxf(r0, r1), fmaxf(r2, r3)), r4);
    float e0 = __expf(r0 - mx), e1 = __expf(r1 - mx), e2 = __expf(r2 - mx);
    float e3 = __expf(r3 - mx), e4 = __expf(r4 - mx);
    const float inv = 1.f / (e0 + e1 + e2 + e3 + e4);
    e0 *= inv; e1 *= inv; e2 *= inv; e3 *= inv; e4 *= inv;
    const size_t orow = ((size_t)((bi * 5 + t5) * 257) + 1 + j) * 512 + hd * 64;
#pragma unroll
    for (int d = 0; d < 64; d += 8) {
        u16x8 o8;
#pragma unroll
        for (int jj = 0; jj < 8; jj++) {
            float o = e0 * vaS[0][d + jj] + e1 * vaS[1][d + jj] + e2 * vaS[2][d + jj] +
                      e3 * vaS[3][d + jj] + e4 * vaS[4][d + jj];
            o8[jj] = f2bf(o);
        }
        *(u16x8*)&cat[orow + d] = o8;
    }
}

extern "C" void kernel_launch(void* const* d_in, const int* in_sizes, int n_in,
                              void* d_out, int out_size, void* d_ws, size_t ws_size,
                              hipStream_t stream) {
    const float* x    = (const float*)d_in[0];  // (160,257,512) f32
    const float* mask = (const float*)d_in[1];  // (160,256) f32
    const float* Wv   = (const float*)d_in[2];  // (512,1536) f32
    const float* Wa   = (const float*)d_in[3];  // (512,1536) f32
    const float* Wo   = (const float*)d_in[4];  // (512,512) f32
    const float* bo   = (const float*)d_in[5];  // (512,) f32
    float* out = (float*)d_out;

    char* ws = (char*)d_ws;
    u16* xb   = (u16*)(ws);                   // 41120*512*2 = 42,106,880 B
    u16* WvT  = (u16*)(ws + 42106880);        // 1,572,864 B
    u16* WaT  = (u16*)(ws + 43679744);        // 1,572,864 B
    u16* WoT  = (u16*)(ws + 45252608);        //   524,288 B
    u16* aqkv = (u16*)(ws + 45776896);        //   491,520 B
    u16* vqkv = (u16*)(ws + 46268416);        // 40960*1536*2 = 125,829,120 B
    u16* cat  = (u16*)(ws + 172097536);       // 42,106,880 B  -> total ~214.2 MB
    // xb is dead after the two projection GEMMs; reuse it as av scratch:
    float* pglob  = (float*)(ws);             // 1280*1280*4 = 6,553,600 B
    float* avpart = (float*)(ws + 6553600);   // 8*1280*64*4 = 2,621,440 B

    f32_to_bf16<<<dim3(10280), 256, 0, stream>>>(x, xb, 41120 * 512);
    transpose_f32_bf16<<<dim3(192), 256, 0, stream>>>(Wv, WvT, 512, 1536);
    transpose_f32_bf16<<<dim3(192), 256, 0, stream>>>(Wa, WaT, 512, 1536);
    transpose_f32_bf16<<<dim3(64),  256, 0, stream>>>(Wo, WoT, 512, 512);

    // v_qkv = V @ Wv_qkv   (V rows = xb[i*257 + 1 + j])
    gemm_k<1, 0><<<dim3(12, 320), 256, 0, stream>>>(xb, WvT, vqkv, nullptr, 40960, 1536, 512);
    // a_qkv = A @ Wa_qkv   (A rows = xb[i*257])
    gemm_k<2, 0><<<dim3(12, 2), 256, 0, stream>>>(xb, WaT, aqkv, nullptr, 160, 1536, 512);

    // attn_av decomposed (xb is dead now)
    av_scores<<<dim3(1280), 256, 0, stream>>>(vqkv, aqkv, pglob);
    av_softmax<<<dim3(320), 256, 0, stream>>>(pglob);
    av_pv<<<dim3(2048), 320, 0, stream>>>(vqkv, pglob, avpart);
    av_write<<<dim3(320), 256, 0, stream>>>(avpart, cat);

    attn_va<<<dim3(1280), 256, 0, stream>>>(vqkv, aqkv, mask, cat);

    // out = cat @ Wo + bo   (float out)
    gemm_k<0, 1><<<dim3(4, 322), 256, 0, stream>>>(cat, WoT, out, bo, 41120, 512, 512);
}